// Round 18
// baseline (137.083 us; speedup 1.0000x reference)
//
#include <hip/hip_runtime.h>

#define SDIM 2048
#define EDIM 768
#define HDIM 12
#define DDIM 64
#define BDIM 4
#define MROWS (BDIM * SDIM)   // 8192
#define NQKV (3 * EDIM)       // 2304
#define NBH (BDIM * HDIM)     // 48
#define NTILE 32              // 2048 / 64 q-tiles
#define NPAIR 16

typedef __attribute__((ext_vector_type(8))) short s16x8;   // 8 bf16
typedef __attribute__((ext_vector_type(4))) float f32x4;
typedef __attribute__((ext_vector_type(2))) unsigned int u32x2;

__device__ __forceinline__ short f2b(float x) {
  union { float f; unsigned u; } v; v.f = x;
  unsigned r = v.u + 0x7fffu + ((v.u >> 16) & 1u);
  return (short)(r >> 16);
}

__device__ __forceinline__ unsigned cvtpk(float lo, float hi) {
  unsigned r;
  asm volatile("v_cvt_pk_bf16_f32 %0, %1, %2" : "=v"(r) : "v"(lo), "v"(hi));
  return r;
}

// bare v_exp_f32 (2^x)
__device__ __forceinline__ float fexp2(float x) {
  float r;
  asm("v_exp_f32 %0, %1" : "=v"(r) : "v"(x));
  return r;
}

__device__ __forceinline__ void gld16(const void* g, void* l) {
  __builtin_amdgcn_global_load_lds(
      (const __attribute__((address_space(1))) unsigned int*)g,
      (__attribute__((address_space(3))) unsigned int*)l, 16, 0, 0);
}

// ---------------- fused preprocessing: convert x + transpose both weights ----
// Transpose writes vectorized: packed ushort2 (4 B/lane, full-wave 128 B rows).
__global__ __launch_bounds__(256) void preproc(
    const float* __restrict__ x, const float* __restrict__ wqkv,
    const float* __restrict__ wproj, short* __restrict__ xb,
    short* __restrict__ wqkvt, short* __restrict__ wprojt) {
  int bid = blockIdx.x;
  if (bid < 1536) {
    int i = bid * 256 + threadIdx.x;
    const int n4 = MROWS * EDIM / 4;
    for (; i < n4; i += 1536 * 256) {
      float4 v = ((const float4*)x)[i];
      short4 o;
      o.x = f2b(v.x); o.y = f2b(v.y); o.z = f2b(v.z); o.w = f2b(v.w);
      ((short4*)xb)[i] = o;
    }
    return;
  }
  const float* in; short* out; int K, N, t;
  if (bid < 1536 + 1728) { t = bid - 1536; in = wqkv; out = wqkvt; K = EDIM; N = NQKV; }
  else { t = bid - 1536 - 1728; in = wproj; out = wprojt; K = EDIM; N = EDIM; }
  const int ntx = N / 32;
  int n0 = (t % ntx) * 32, k0 = (t / ntx) * 32;
  __shared__ float tb[32][33];
  int tx = threadIdx.x & 31, ty = threadIdx.x >> 5;  // ty 0..7
#pragma unroll
  for (int i = 0; i < 4; ++i)
    tb[ty + 8 * i][tx] = in[(size_t)(k0 + ty + 8 * i) * N + n0 + tx];
  __syncthreads();
  // packed writes: thread -> row r = n0 + (tid>>4) (+16), k-pair p = tid&15
  const int rr = threadIdx.x >> 4;   // 0..15
  const int pp = threadIdx.x & 15;   // 0..15
#pragma unroll
  for (int i = 0; i < 2; ++i) {
    int row = rr + 16 * i;
    unsigned lo = (unsigned short)f2b(tb[2 * pp][row]);
    unsigned hi = (unsigned short)f2b(tb[2 * pp + 1][row]);
    *(unsigned*)(out + (size_t)(n0 + row) * K + k0 + 2 * pp) = lo | (hi << 16);
  }
}

// ---------------- QKV GEMM: R7-proven 128x128, ring-3, counted vmcnt(4) -----
__global__ __launch_bounds__(256) void gemm_qkv(
    const short* __restrict__ A, const short* __restrict__ Bt,
    const float* __restrict__ bias, short* __restrict__ qout,
    short* __restrict__ kout, short* __restrict__ vout) {
  __shared__ char lds[3][16384];
  const int tid = threadIdx.x;
  const int l = tid & 63, w = tid >> 6;
  const int lr = l & 15, g = l >> 4;
  const int K = EDIM;

  const int chunk = gridDim.x >> 3;  // 1152 % 8 == 0
  const int sid = (blockIdx.x & 7) * chunk + (blockIdx.x >> 3);
  const int ntx = NQKV >> 7;  // 18
  const int bm = (sid / ntx) * 128, bn = (sid % ntx) * 128;
  const int wm = w >> 1, wn = w & 1;

  const int srow = w * 32 + (l >> 2);
  const int sc8 = (((l & 3) ^ ((l >> 3) & 3)) << 3);
  const short* Ap0 = A + (size_t)(bm + srow) * K + sc8;
  const short* Bp0 = Bt + (size_t)(bn + srow) * K + sc8;

  f32x4 acc[4][4];
  const f32x4 z4 = {0.f, 0.f, 0.f, 0.f};
#pragma unroll
  for (int m = 0; m < 4; ++m)
#pragma unroll
    for (int n = 0; n < 4; ++n) acc[m][n] = z4;

#define STAGE(dst, t)                          \
  {                                            \
    char* Ad = (dst) + w * 2048;               \
    const short* Ap = Ap0 + (t) * 32;          \
    const short* Bp = Bp0 + (t) * 32;          \
    gld16(Ap, Ad);                             \
    gld16(Ap + 16 * K, Ad + 1024);             \
    gld16(Bp, Ad + 8192);                      \
    gld16(Bp + 16 * K, Ad + 9216);             \
  }

  const int nt = K >> 5;  // 24
  STAGE(lds[0], 0);
  STAGE(lds[1], 1);
  asm volatile("s_waitcnt vmcnt(4)" ::: "memory");
  __builtin_amdgcn_s_barrier();

  const int swz = ((lr >> 1) & 3) << 4;
  int bc = 0;
  for (int t = 0; t < nt; ++t) {
    if (t + 2 < nt) {
      int bs = bc + 2; if (bs >= 3) bs -= 3;
      STAGE(lds[bs], t + 2);
    }
    const char* Ab = lds[bc];
    const char* Bb = lds[bc] + 8192;
    s16x8 af[4], bfr[4];
#pragma unroll
    for (int m = 0; m < 4; ++m)
      af[m] = *(const s16x8*)(Ab + (wm * 64 + m * 16 + lr) * 64 + ((g << 4) ^ swz));
#pragma unroll
    for (int n = 0; n < 4; ++n)
      bfr[n] = *(const s16x8*)(Bb + (wn * 64 + n * 16 + lr) * 64 + ((g << 4) ^ swz));
    __builtin_amdgcn_s_setprio(1);
#pragma unroll
    for (int m = 0; m < 4; ++m)
#pragma unroll
      for (int n = 0; n < 4; ++n)
        acc[m][n] = __builtin_amdgcn_mfma_f32_16x16x32_bf16(af[m], bfr[n],
                                                            acc[m][n], 0, 0, 0);
    __builtin_amdgcn_s_setprio(0);
    if (t + 2 < nt) {
      asm volatile("s_waitcnt vmcnt(4)" ::: "memory");
      __builtin_amdgcn_s_barrier();
    } else if (t + 1 < nt) {
      asm volatile("s_waitcnt vmcnt(0)" ::: "memory");
      __builtin_amdgcn_s_barrier();
    }
    if (++bc == 3) bc = 0;
  }
#undef STAGE

#pragma unroll
  for (int m = 0; m < 4; ++m) {
    int rbase = bm + wm * 64 + m * 16 + g * 4;
#pragma unroll
    for (int n = 0; n < 4; ++n) {
      int col = bn + wn * 64 + n * 16 + lr;
      float bv = bias[col];
      int which = (col >= 1536) ? 2 : (col >= 768 ? 1 : 0);
      int rem = col - which * 768;
      int h = rem >> 6, d = rem & 63;
#pragma unroll
      for (int i = 0; i < 4; ++i) {
        int r = rbase + i;
        int bb = r >> 11, s = r & 2047;
        short o = f2b(acc[m][n][i] + bv);
        size_t bh = (size_t)bb * HDIM + h;
        if (which == 0)      qout[(bh * SDIM + s) * DDIM + d] = o;
        else if (which == 1) kout[(bh * SDIM + s) * DDIM + d] = o;
        else                 vout[(bh * DDIM + d) * SDIM + s] = o;  // V^T
      }
    }
  }
}

// ---------------- proj GEMM (R10-proven 128x128 ring-3, fp32 out) -----------
__global__ __launch_bounds__(256) void gemm_proj(
    const short* __restrict__ A, const short* __restrict__ Bt,
    const float* __restrict__ bias, int M, int N, int K,
    float* __restrict__ fout) {
  __shared__ char lds[3][16384];
  const int tid = threadIdx.x;
  const int l = tid & 63, w = tid >> 6;
  const int lr = l & 15, g = l >> 4;

  const int chunk = gridDim.x >> 3;
  const int sid = (blockIdx.x & 7) * chunk + (blockIdx.x >> 3);
  const int ntx = N >> 7;
  const int bm = (sid / ntx) * 128, bn = (sid % ntx) * 128;
  const int wm = w >> 1, wn = w & 1;

  const int srow = w * 32 + (l >> 2);
  const int sc8 = (((l & 3) ^ ((l >> 3) & 3)) << 3);
  const short* Ap0 = A + (size_t)(bm + srow) * K + sc8;
  const short* Bp0 = Bt + (size_t)(bn + srow) * K + sc8;

  f32x4 acc[4][4];
  const f32x4 z4 = {0.f, 0.f, 0.f, 0.f};
#pragma unroll
  for (int m = 0; m < 4; ++m)
#pragma unroll
    for (int n = 0; n < 4; ++n) acc[m][n] = z4;

#define STAGE(dst, t)                          \
  {                                            \
    char* Ad = (dst) + w * 2048;               \
    const short* Ap = Ap0 + (t) * 32;          \
    const short* Bp = Bp0 + (t) * 32;          \
    gld16(Ap, Ad);                             \
    gld16(Ap + 16 * K, Ad + 1024);             \
    gld16(Bp, Ad + 8192);                      \
    gld16(Bp + 16 * K, Ad + 9216);             \
  }

  const int nt = K >> 5;
  STAGE(lds[0], 0);
  STAGE(lds[1], 1);
  asm volatile("s_waitcnt vmcnt(4)" ::: "memory");
  __builtin_amdgcn_s_barrier();

  const int swz = ((lr >> 1) & 3) << 4;
  int bc = 0;
  for (int t = 0; t < nt; ++t) {
    if (t + 2 < nt) {
      int bs = bc + 2; if (bs >= 3) bs -= 3;
      STAGE(lds[bs], t + 2);
    }
    const char* Ab = lds[bc];
    const char* Bb = lds[bc] + 8192;
    s16x8 af[4], bfr[4];
#pragma unroll
    for (int m = 0; m < 4; ++m)
      af[m] = *(const s16x8*)(Ab + (wm * 64 + m * 16 + lr) * 64 + ((g << 4) ^ swz));
#pragma unroll
    for (int n = 0; n < 4; ++n)
      bfr[n] = *(const s16x8*)(Bb + (wn * 64 + n * 16 + lr) * 64 + ((g << 4) ^ swz));
    __builtin_amdgcn_s_setprio(1);
#pragma unroll
    for (int m = 0; m < 4; ++m)
#pragma unroll
      for (int n = 0; n < 4; ++n)
        acc[m][n] = __builtin_amdgcn_mfma_f32_16x16x32_bf16(af[m], bfr[n],
                                                            acc[m][n], 0, 0, 0);
    __builtin_amdgcn_s_setprio(0);
    if (t + 2 < nt) {
      asm volatile("s_waitcnt vmcnt(4)" ::: "memory");
      __builtin_amdgcn_s_barrier();
    } else if (t + 1 < nt) {
      asm volatile("s_waitcnt vmcnt(0)" ::: "memory");
      __builtin_amdgcn_s_barrier();
    }
    if (++bc == 3) bc = 0;
  }
#undef STAGE

#pragma unroll
  for (int m = 0; m < 4; ++m) {
    int rbase = bm + wm * 64 + m * 16 + g * 4;
#pragma unroll
    for (int n = 0; n < 4; ++n) {
      int col = bn + wn * 64 + n * 16 + lr;
      float bv = bias[col];
#pragma unroll
      for (int i = 0; i < 4; ++i)
        fout[(size_t)(rbase + i) * N + col] = acc[m][n][i] + bv;
    }
  }
}

// ---------------- flash attention v4: counted-vmcnt K/V pipeline ----------
__global__ __launch_bounds__(256, 3) void attn_mfma4(
    const short* __restrict__ qb, const short* __restrict__ kb,
    const short* __restrict__ vb, short* __restrict__ ao) {
  __shared__ short kvbuf[2][8192];
  __shared__ short pstrip[4][1024];

  const int tid = threadIdx.x;
  const int l = tid & 63, w = tid >> 6;
  const int lr = l & 15, g = l >> 4;
  const int swz = (lr & 7) << 4;

  const int lin = blockIdx.x;
  const int xcd = lin & 7;
  const int idx = lin >> 3;
  const int bh = xcd * 6 + (idx >> 4);
  const int pair = idx & 15;
  const int tiles[2] = {NTILE - 1 - pair, pair};

  const int b = bh / HDIM, h = bh % HDIM;
  const size_t base = (size_t)bh * SDIM * DDIM;

  const int srow = w * 16 + (l >> 3);
  const int sc = (l & 7) ^ (srow & 7);
  const size_t koff0 = (size_t)srow * DDIM + sc * 8;
  const size_t koff1 = (size_t)(srow + 8) * DDIM + sc * 8;
  const size_t voff0 = (size_t)srow * SDIM + sc * 8;
  const size_t voff1 = (size_t)(srow + 8) * SDIM + sc * 8;

  const float SC = 0.125f * 1.4426950408889634f;
  char* sw = (char*)pstrip[w];

#define KVSTAGE(buf_, kt_)                                        \
  {                                                               \
    char* kd = (char*)kvbuf[buf_] + w * 2048;                     \
    const short* kp = kb + base + (size_t)(kt_) * 64 * DDIM;      \
    const short* vp = vb + base + (size_t)(kt_) * 64;             \
    gld16(kp + koff0, kd);                                        \
    gld16(kp + koff1, kd + 1024);                                 \
    gld16(vp + voff0, kd + 8192);                                 \
    gld16(vp + voff1, kd + 9216);                                 \
  }

  for (int half = 0; half < 2; ++half) {
    const int tile = tiles[half];
    const int q0w = tile * 64 + w * 16;

    s16x8 qa[2];
#pragma unroll
    for (int s = 0; s < 2; ++s)
      qa[s] = *(const s16x8*)(qb + base + (size_t)(q0w + lr) * DDIM + s * 32 + g * 8);

    const f32x4 z4 = {0.f, 0.f, 0.f, 0.f};
    f32x4 acco[4];
#pragma unroll
    for (int nd = 0; nd < 4; ++nd) acco[nd] = z4;
    float mrun = -1e30f, lsum = 0.f;

    KVSTAGE(0, 0);
    {
      const int t1 = (tile >= 1) ? 1 : 0;
      KVSTAGE(1, t1);
    }

    for (int kt = 0; kt <= tile; ++kt) {
      if (kt < tile) asm volatile("s_waitcnt vmcnt(4)" ::: "memory");
      else           asm volatile("s_waitcnt vmcnt(0)" ::: "memory");
      __builtin_amdgcn_s_barrier();

      const char* Kb = (const char*)kvbuf[kt & 1];
      const char* Vb = Kb + 8192;

      f32x4 sacc[4];
#pragma unroll
      for (int nt = 0; nt < 4; ++nt) sacc[nt] = z4;
      __builtin_amdgcn_s_setprio(1);
#pragma unroll
      for (int s = 0; s < 2; ++s)
#pragma unroll
        for (int nt = 0; nt < 4; ++nt) {
          s16x8 kf = *(const s16x8*)(Kb + nt * 2048 + lr * 128 +
                                     ((s * 64 + g * 16) ^ swz));
          sacc[nt] = __builtin_amdgcn_mfma_f32_16x16x32_bf16(kf, qa[s],
                                                             sacc[nt], 0, 0, 0);
        }
      __builtin_amdgcn_s_setprio(0);

      if (kt == tile) {
        const int rloc = w * 16 + lr;
#pragma unroll
        for (int nt = 0; nt < 4; ++nt)
#pragma unroll
          for (int i = 0; i < 4; ++i)
            if (nt * 16 + g * 4 + i > rloc) sacc[nt][i] = -1e30f;
      }

      float t0 = fmaxf(fmaxf(sacc[0][0], sacc[0][1]), fmaxf(sacc[0][2], sacc[0][3]));
      float t1 = fmaxf(fmaxf(sacc[1][0], sacc[1][1]), fmaxf(sacc[1][2], sacc[1][3]));
      float t2 = fmaxf(fmaxf(sacc[2][0], sacc[2][1]), fmaxf(sacc[2][2], sacc[2][3]));
      float t3 = fmaxf(fmaxf(sacc[3][0], sacc[3][1]), fmaxf(sacc[3][2], sacc[3][3]));
      float pmax = fmaxf(fmaxf(t0, t1), fmaxf(t2, t3));
      pmax = fmaxf(pmax, __shfl_xor(pmax, 16, 64));
      pmax = fmaxf(pmax, __shfl_xor(pmax, 32, 64));

      if (__any(pmax > mrun + 44.0f)) {
        float nm = fmaxf(mrun, pmax);
        float al = fexp2((mrun - nm) * SC);
        lsum *= al;
#pragma unroll
        for (int nd = 0; nd < 4; ++nd)
#pragma unroll
          for (int i = 0; i < 4; ++i) acco[nd][i] *= al;
        mrun = nm;
      }

      const float msc = mrun * SC;
#pragma unroll
      for (int nt = 0; nt < 4; ++nt) {
        float p0 = fexp2(__builtin_fmaf(sacc[nt][0], SC, -msc));
        float p1 = fexp2(__builtin_fmaf(sacc[nt][1], SC, -msc));
        float p2 = fexp2(__builtin_fmaf(sacc[nt][2], SC, -msc));
        float p3 = fexp2(__builtin_fmaf(sacc[nt][3], SC, -msc));
        lsum += (p0 + p1) + (p2 + p3);
        u32x2 pk = {cvtpk(p0, p1), cvtpk(p2, p3)};
        *(u32x2*)(sw + lr * 128 + (((nt * 32 + g * 8) ^ swz))) = pk;
      }

      __builtin_amdgcn_s_setprio(1);
#pragma unroll
      for (int s = 0; s < 2; ++s) {
        s16x8 pf = *(const s16x8*)(sw + lr * 128 + ((s * 64 + g * 16) ^ swz));
#pragma unroll
        for (int nd = 0; nd < 4; ++nd) {
          s16x8 vf = *(const s16x8*)(Vb + nd * 2048 + lr * 128 +
                                     ((s * 64 + g * 16) ^ swz));
          acco[nd] = __builtin_amdgcn_mfma_f32_16x16x32_bf16(vf, pf,
                                                             acco[nd], 0, 0, 0);
        }
      }
      __builtin_amdgcn_s_setprio(0);

      __builtin_amdgcn_s_barrier();  // all waves done reading kvbuf[kt&1]
      if (kt + 2 <= tile) KVSTAGE(kt & 1, kt + 2);
    }

    lsum += __shfl_xor(lsum, 16, 64);
    lsum += __shfl_xor(lsum, 32, 64);
    float inv = 1.0f / lsum;
    size_t orow = ((size_t)b * SDIM + q0w + lr) * EDIM + h * DDIM;
#pragma unroll
    for (int nd = 0; nd < 4; ++nd) {
      unsigned lo = cvtpk(acco[nd][0] * inv, acco[nd][1] * inv);
      unsigned hi = cvtpk(acco[nd][2] * inv, acco[nd][3] * inv);
      *(unsigned*)(ao + orow + nd * 16 + g * 4) = lo;
      *(unsigned*)(ao + orow + nd * 16 + g * 4 + 2) = hi;
    }
  }
#undef KVSTAGE
}

extern "C" void kernel_launch(void* const* d_in, const int* in_sizes, int n_in,
                              void* d_out, int out_size, void* d_ws,
                              size_t ws_size, hipStream_t stream) {
  const float* x = (const float*)d_in[0];
  const float* w_qkv = (const float*)d_in[1];
  const float* b_qkv = (const float*)d_in[2];
  const float* w_proj = (const float*)d_in[3];
  const float* b_proj = (const float*)d_in[4];
  float* out = (float*)d_out;

  char* p = (char*)d_ws;
  short* xb = (short*)p;      p += (size_t)MROWS * EDIM * 2;
  short* wqkvt = (short*)p;   p += (size_t)NQKV * EDIM * 2;
  short* wprojt = (short*)p;  p += (size_t)EDIM * EDIM * 2;
  short* qbuf = (short*)p;    p += (size_t)NBH * SDIM * DDIM * 2;
  short* kbuf = (short*)p;    p += (size_t)NBH * SDIM * DDIM * 2;
  short* vbuf = (short*)p;    p += (size_t)NBH * SDIM * DDIM * 2;
  short* aob = (short*)p;     p += (size_t)MROWS * EDIM * 2;

  dim3 blk(256);
  preproc<<<dim3(1536 + 1728 + 576), blk, 0, stream>>>(x, w_qkv, w_proj, xb,
                                                       wqkvt, wprojt);
  // QKV: 128x128 tiles -> 64 * 18 = 1152 blocks (% 8 == 0)
  gemm_qkv<<<dim3((MROWS / 128) * (NQKV / 128)), blk, 0, stream>>>(
      xb, wqkvt, b_qkv, qbuf, kbuf, vbuf);
  attn_mfma4<<<dim3(NPAIR * NBH), blk, 0, stream>>>(qbuf, kbuf, vbuf, aob);
  // proj: 128x128 tiles -> 64 * 6 = 384 blocks (% 8 == 0)
  gemm_proj<<<dim3((MROWS / 128) * (EDIM / 128)), blk, 0, stream>>>(
      aob, wprojt, b_proj, MROWS, EDIM, EDIM, out);
}

// Round 19
// 136.731 us; speedup vs baseline: 1.0026x; 1.0026x over previous
//
#include <hip/hip_runtime.h>

#define SDIM 2048
#define EDIM 768
#define HDIM 12
#define DDIM 64
#define BDIM 4
#define MROWS (BDIM * SDIM)   // 8192
#define NQKV (3 * EDIM)       // 2304
#define NBH (BDIM * HDIM)     // 48
#define NTILE 32              // 2048 / 64 q-tiles
#define NPAIR 16

typedef __attribute__((ext_vector_type(8))) short s16x8;   // 8 bf16
typedef __attribute__((ext_vector_type(4))) float f32x4;
typedef __attribute__((ext_vector_type(2))) unsigned int u32x2;

__device__ __forceinline__ short f2b(float x) {
  union { float f; unsigned u; } v; v.f = x;
  unsigned r = v.u + 0x7fffu + ((v.u >> 16) & 1u);
  return (short)(r >> 16);
}

__device__ __forceinline__ unsigned cvtpk(float lo, float hi) {
  unsigned r;
  asm volatile("v_cvt_pk_bf16_f32 %0, %1, %2" : "=v"(r) : "v"(lo), "v"(hi));
  return r;
}

// bare v_exp_f32 (2^x)
__device__ __forceinline__ float fexp2(float x) {
  float r;
  asm("v_exp_f32 %0, %1" : "=v"(r) : "v"(x));
  return r;
}

__device__ __forceinline__ void gld16(const void* g, void* l) {
  __builtin_amdgcn_global_load_lds(
      (const __attribute__((address_space(1))) unsigned int*)g,
      (__attribute__((address_space(3))) unsigned int*)l, 16, 0, 0);
}

// ---------------- fused preprocessing: convert x + transpose both weights ----
__global__ __launch_bounds__(256) void preproc(
    const float* __restrict__ x, const float* __restrict__ wqkv,
    const float* __restrict__ wproj, short* __restrict__ xb,
    short* __restrict__ wqkvt, short* __restrict__ wprojt) {
  int bid = blockIdx.x;
  if (bid < 1536) {
    int i = bid * 256 + threadIdx.x;
    const int n4 = MROWS * EDIM / 4;
    for (; i < n4; i += 1536 * 256) {
      float4 v = ((const float4*)x)[i];
      short4 o;
      o.x = f2b(v.x); o.y = f2b(v.y); o.z = f2b(v.z); o.w = f2b(v.w);
      ((short4*)xb)[i] = o;
    }
    return;
  }
  const float* in; short* out; int K, N, t;
  if (bid < 1536 + 1728) { t = bid - 1536; in = wqkv; out = wqkvt; K = EDIM; N = NQKV; }
  else { t = bid - 1536 - 1728; in = wproj; out = wprojt; K = EDIM; N = EDIM; }
  const int ntx = N / 32;
  int n0 = (t % ntx) * 32, k0 = (t / ntx) * 32;
  __shared__ float tb[32][33];
  int tx = threadIdx.x & 31, ty = threadIdx.x >> 5;  // ty 0..7
#pragma unroll
  for (int i = 0; i < 4; ++i)
    tb[ty + 8 * i][tx] = in[(size_t)(k0 + ty + 8 * i) * N + n0 + tx];
  __syncthreads();
  // packed writes: thread -> row r = n0 + (tid>>4) (+16), k-pair p = tid&15
  const int rr = threadIdx.x >> 4;   // 0..15
  const int pp = threadIdx.x & 15;   // 0..15
#pragma unroll
  for (int i = 0; i < 2; ++i) {
    int row = rr + 16 * i;
    unsigned lo = (unsigned short)f2b(tb[2 * pp][row]);
    unsigned hi = (unsigned short)f2b(tb[2 * pp + 1][row]);
    *(unsigned*)(out + (size_t)(n0 + row) * K + k0 + 2 * pp) = lo | (hi << 16);
  }
}

// ---------------- QKV GEMM: 128x128, ring-3, counted vmcnt(4) ----------------
__global__ __launch_bounds__(256) void gemm_qkv(
    const short* __restrict__ A, const short* __restrict__ Bt,
    const float* __restrict__ bias, short* __restrict__ qout,
    short* __restrict__ kout, short* __restrict__ vout) {
  __shared__ char lds[3][16384];
  const int tid = threadIdx.x;
  const int l = tid & 63, w = tid >> 6;
  const int lr = l & 15, g = l >> 4;
  const int K = EDIM;

  const int chunk = gridDim.x >> 3;  // 1152 % 8 == 0
  const int sid = (blockIdx.x & 7) * chunk + (blockIdx.x >> 3);
  const int ntx = NQKV >> 7;  // 18
  const int bm = (sid / ntx) * 128, bn = (sid % ntx) * 128;
  const int wm = w >> 1, wn = w & 1;

  const int srow = w * 32 + (l >> 2);
  const int sc8 = (((l & 3) ^ ((l >> 3) & 3)) << 3);
  const short* Ap0 = A + (size_t)(bm + srow) * K + sc8;
  const short* Bp0 = Bt + (size_t)(bn + srow) * K + sc8;

  f32x4 acc[4][4];
  const f32x4 z4 = {0.f, 0.f, 0.f, 0.f};
#pragma unroll
  for (int m = 0; m < 4; ++m)
#pragma unroll
    for (int n = 0; n < 4; ++n) acc[m][n] = z4;

#define STAGE(dst, t)                          \
  {                                            \
    char* Ad = (dst) + w * 2048;               \
    const short* Ap = Ap0 + (t) * 32;          \
    const short* Bp = Bp0 + (t) * 32;          \
    gld16(Ap, Ad);                             \
    gld16(Ap + 16 * K, Ad + 1024);             \
    gld16(Bp, Ad + 8192);                      \
    gld16(Bp + 16 * K, Ad + 9216);             \
  }

  const int nt = K >> 5;  // 24
  STAGE(lds[0], 0);
  STAGE(lds[1], 1);
  asm volatile("s_waitcnt vmcnt(4)" ::: "memory");
  __builtin_amdgcn_s_barrier();

  const int swz = ((lr >> 1) & 3) << 4;
  int bc = 0;
  for (int t = 0; t < nt; ++t) {
    if (t + 2 < nt) {
      int bs = bc + 2; if (bs >= 3) bs -= 3;
      STAGE(lds[bs], t + 2);
    }
    const char* Ab = lds[bc];
    const char* Bb = lds[bc] + 8192;
    s16x8 af[4], bfr[4];
#pragma unroll
    for (int m = 0; m < 4; ++m)
      af[m] = *(const s16x8*)(Ab + (wm * 64 + m * 16 + lr) * 64 + ((g << 4) ^ swz));
#pragma unroll
    for (int n = 0; n < 4; ++n)
      bfr[n] = *(const s16x8*)(Bb + (wn * 64 + n * 16 + lr) * 64 + ((g << 4) ^ swz));
    __builtin_amdgcn_s_setprio(1);
#pragma unroll
    for (int m = 0; m < 4; ++m)
#pragma unroll
      for (int n = 0; n < 4; ++n)
        acc[m][n] = __builtin_amdgcn_mfma_f32_16x16x32_bf16(af[m], bfr[n],
                                                            acc[m][n], 0, 0, 0);
    __builtin_amdgcn_s_setprio(0);
    if (t + 2 < nt) {
      asm volatile("s_waitcnt vmcnt(4)" ::: "memory");
      __builtin_amdgcn_s_barrier();
    } else if (t + 1 < nt) {
      asm volatile("s_waitcnt vmcnt(0)" ::: "memory");
      __builtin_amdgcn_s_barrier();
    }
    if (++bc == 3) bc = 0;
  }
#undef STAGE

#pragma unroll
  for (int m = 0; m < 4; ++m) {
    int rbase = bm + wm * 64 + m * 16 + g * 4;
#pragma unroll
    for (int n = 0; n < 4; ++n) {
      int col = bn + wn * 64 + n * 16 + lr;
      float bv = bias[col];
      int which = (col >= 1536) ? 2 : (col >= 768 ? 1 : 0);
      int rem = col - which * 768;
      int h = rem >> 6, d = rem & 63;
#pragma unroll
      for (int i = 0; i < 4; ++i) {
        int r = rbase + i;
        int bb = r >> 11, s = r & 2047;
        short o = f2b(acc[m][n][i] + bv);
        size_t bh = (size_t)bb * HDIM + h;
        if (which == 0)      qout[(bh * SDIM + s) * DDIM + d] = o;
        else if (which == 1) kout[(bh * SDIM + s) * DDIM + d] = o;
        else                 vout[(bh * DDIM + d) * SDIM + s] = o;  // V^T
      }
    }
  }
}

// ---------------- proj GEMM (128x128 ring-3, fp32 out) ----------------------
__global__ __launch_bounds__(256) void gemm_proj(
    const short* __restrict__ A, const short* __restrict__ Bt,
    const float* __restrict__ bias, int M, int N, int K,
    float* __restrict__ fout) {
  __shared__ char lds[3][16384];
  const int tid = threadIdx.x;
  const int l = tid & 63, w = tid >> 6;
  const int lr = l & 15, g = l >> 4;

  const int chunk = gridDim.x >> 3;
  const int sid = (blockIdx.x & 7) * chunk + (blockIdx.x >> 3);
  const int ntx = N >> 7;
  const int bm = (sid / ntx) * 128, bn = (sid % ntx) * 128;
  const int wm = w >> 1, wn = w & 1;

  const int srow = w * 32 + (l >> 2);
  const int sc8 = (((l & 3) ^ ((l >> 3) & 3)) << 3);
  const short* Ap0 = A + (size_t)(bm + srow) * K + sc8;
  const short* Bp0 = Bt + (size_t)(bn + srow) * K + sc8;

  f32x4 acc[4][4];
  const f32x4 z4 = {0.f, 0.f, 0.f, 0.f};
#pragma unroll
  for (int m = 0; m < 4; ++m)
#pragma unroll
    for (int n = 0; n < 4; ++n) acc[m][n] = z4;

#define STAGE(dst, t)                          \
  {                                            \
    char* Ad = (dst) + w * 2048;               \
    const short* Ap = Ap0 + (t) * 32;          \
    const short* Bp = Bp0 + (t) * 32;          \
    gld16(Ap, Ad);                             \
    gld16(Ap + 16 * K, Ad + 1024);             \
    gld16(Bp, Ad + 8192);                      \
    gld16(Bp + 16 * K, Ad + 9216);             \
  }

  const int nt = K >> 5;
  STAGE(lds[0], 0);
  STAGE(lds[1], 1);
  asm volatile("s_waitcnt vmcnt(4)" ::: "memory");
  __builtin_amdgcn_s_barrier();

  const int swz = ((lr >> 1) & 3) << 4;
  int bc = 0;
  for (int t = 0; t < nt; ++t) {
    if (t + 2 < nt) {
      int bs = bc + 2; if (bs >= 3) bs -= 3;
      STAGE(lds[bs], t + 2);
    }
    const char* Ab = lds[bc];
    const char* Bb = lds[bc] + 8192;
    s16x8 af[4], bfr[4];
#pragma unroll
    for (int m = 0; m < 4; ++m)
      af[m] = *(const s16x8*)(Ab + (wm * 64 + m * 16 + lr) * 64 + ((g << 4) ^ swz));
#pragma unroll
    for (int n = 0; n < 4; ++n)
      bfr[n] = *(const s16x8*)(Bb + (wn * 64 + n * 16 + lr) * 64 + ((g << 4) ^ swz));
    __builtin_amdgcn_s_setprio(1);
#pragma unroll
    for (int m = 0; m < 4; ++m)
#pragma unroll
      for (int n = 0; n < 4; ++n)
        acc[m][n] = __builtin_amdgcn_mfma_f32_16x16x32_bf16(af[m], bfr[n],
                                                            acc[m][n], 0, 0, 0);
    __builtin_amdgcn_s_setprio(0);
    if (t + 2 < nt) {
      asm volatile("s_waitcnt vmcnt(4)" ::: "memory");
      __builtin_amdgcn_s_barrier();
    } else if (t + 1 < nt) {
      asm volatile("s_waitcnt vmcnt(0)" ::: "memory");
      __builtin_amdgcn_s_barrier();
    }
    if (++bc == 3) bc = 0;
  }
#undef STAGE

#pragma unroll
  for (int m = 0; m < 4; ++m) {
    int rbase = bm + wm * 64 + m * 16 + g * 4;
#pragma unroll
    for (int n = 0; n < 4; ++n) {
      int col = bn + wn * 64 + n * 16 + lr;
      float bv = bias[col];
#pragma unroll
      for (int i = 0; i < 4; ++i)
        fout[(size_t)(rbase + i) * N + col] = acc[m][n][i] + bv;
    }
  }
}

// ---------------- flash attention v4: counted-vmcnt K/V pipeline ----------
__global__ __launch_bounds__(256, 3) void attn_mfma4(
    const short* __restrict__ qb, const short* __restrict__ kb,
    const short* __restrict__ vb, short* __restrict__ ao) {
  __shared__ short kvbuf[2][8192];
  __shared__ short pstrip[4][1024];

  const int tid = threadIdx.x;
  const int l = tid & 63, w = tid >> 6;
  const int lr = l & 15, g = l >> 4;
  const int swz = (lr & 7) << 4;

  const int lin = blockIdx.x;
  const int xcd = lin & 7;
  const int idx = lin >> 3;
  const int bh = xcd * 6 + (idx >> 4);
  const int pair = idx & 15;
  const int tiles[2] = {NTILE - 1 - pair, pair};

  const int b = bh / HDIM, h = bh % HDIM;
  const size_t base = (size_t)bh * SDIM * DDIM;

  const int srow = w * 16 + (l >> 3);
  const int sc = (l & 7) ^ (srow & 7);
  const size_t koff0 = (size_t)srow * DDIM + sc * 8;
  const size_t koff1 = (size_t)(srow + 8) * DDIM + sc * 8;
  const size_t voff0 = (size_t)srow * SDIM + sc * 8;
  const size_t voff1 = (size_t)(srow + 8) * SDIM + sc * 8;

  const float SC = 0.125f * 1.4426950408889634f;
  char* sw = (char*)pstrip[w];

#define KVSTAGE(buf_, kt_)                                        \
  {                                                               \
    char* kd = (char*)kvbuf[buf_] + w * 2048;                     \
    const short* kp = kb + base + (size_t)(kt_) * 64 * DDIM;      \
    const short* vp = vb + base + (size_t)(kt_) * 64;             \
    gld16(kp + koff0, kd);                                        \
    gld16(kp + koff1, kd + 1024);                                 \
    gld16(vp + voff0, kd + 8192);                                 \
    gld16(vp + voff1, kd + 9216);                                 \
  }

  for (int half = 0; half < 2; ++half) {
    const int tile = tiles[half];
    const int q0w = tile * 64 + w * 16;

    s16x8 qa[2];
#pragma unroll
    for (int s = 0; s < 2; ++s)
      qa[s] = *(const s16x8*)(qb + base + (size_t)(q0w + lr) * DDIM + s * 32 + g * 8);

    const f32x4 z4 = {0.f, 0.f, 0.f, 0.f};
    f32x4 acco[4];
#pragma unroll
    for (int nd = 0; nd < 4; ++nd) acco[nd] = z4;
    float mrun = -1e30f, lsum = 0.f;

    KVSTAGE(0, 0);
    {
      const int t1 = (tile >= 1) ? 1 : 0;
      KVSTAGE(1, t1);
    }

    for (int kt = 0; kt <= tile; ++kt) {
      if (kt < tile) asm volatile("s_waitcnt vmcnt(4)" ::: "memory");
      else           asm volatile("s_waitcnt vmcnt(0)" ::: "memory");
      __builtin_amdgcn_s_barrier();

      const char* Kb = (const char*)kvbuf[kt & 1];
      const char* Vb = Kb + 8192;

      f32x4 sacc[4];
#pragma unroll
      for (int nt = 0; nt < 4; ++nt) sacc[nt] = z4;
      __builtin_amdgcn_s_setprio(1);
#pragma unroll
      for (int s = 0; s < 2; ++s)
#pragma unroll
        for (int nt = 0; nt < 4; ++nt) {
          s16x8 kf = *(const s16x8*)(Kb + nt * 2048 + lr * 128 +
                                     ((s * 64 + g * 16) ^ swz));
          sacc[nt] = __builtin_amdgcn_mfma_f32_16x16x32_bf16(kf, qa[s],
                                                             sacc[nt], 0, 0, 0);
        }
      __builtin_amdgcn_s_setprio(0);

      if (kt == tile) {
        const int rloc = w * 16 + lr;
#pragma unroll
        for (int nt = 0; nt < 4; ++nt)
#pragma unroll
          for (int i = 0; i < 4; ++i)
            if (nt * 16 + g * 4 + i > rloc) sacc[nt][i] = -1e30f;
      }

      float t0 = fmaxf(fmaxf(sacc[0][0], sacc[0][1]), fmaxf(sacc[0][2], sacc[0][3]));
      float t1 = fmaxf(fmaxf(sacc[1][0], sacc[1][1]), fmaxf(sacc[1][2], sacc[1][3]));
      float t2 = fmaxf(fmaxf(sacc[2][0], sacc[2][1]), fmaxf(sacc[2][2], sacc[2][3]));
      float t3 = fmaxf(fmaxf(sacc[3][0], sacc[3][1]), fmaxf(sacc[3][2], sacc[3][3]));
      float pmax = fmaxf(fmaxf(t0, t1), fmaxf(t2, t3));
      pmax = fmaxf(pmax, __shfl_xor(pmax, 16, 64));
      pmax = fmaxf(pmax, __shfl_xor(pmax, 32, 64));

      if (__any(pmax > mrun + 44.0f)) {
        float nm = fmaxf(mrun, pmax);
        float al = fexp2((mrun - nm) * SC);
        lsum *= al;
#pragma unroll
        for (int nd = 0; nd < 4; ++nd)
#pragma unroll
          for (int i = 0; i < 4; ++i) acco[nd][i] *= al;
        mrun = nm;
      }

      const float msc = mrun * SC;
#pragma unroll
      for (int nt = 0; nt < 4; ++nt) {
        float p0 = fexp2(__builtin_fmaf(sacc[nt][0], SC, -msc));
        float p1 = fexp2(__builtin_fmaf(sacc[nt][1], SC, -msc));
        float p2 = fexp2(__builtin_fmaf(sacc[nt][2], SC, -msc));
        float p3 = fexp2(__builtin_fmaf(sacc[nt][3], SC, -msc));
        lsum += (p0 + p1) + (p2 + p3);
        u32x2 pk = {cvtpk(p0, p1), cvtpk(p2, p3)};
        *(u32x2*)(sw + lr * 128 + (((nt * 32 + g * 8) ^ swz))) = pk;
      }

      __builtin_amdgcn_s_setprio(1);
#pragma unroll
      for (int s = 0; s < 2; ++s) {
        s16x8 pf = *(const s16x8*)(sw + lr * 128 + ((s * 64 + g * 16) ^ swz));
#pragma unroll
        for (int nd = 0; nd < 4; ++nd) {
          s16x8 vf = *(const s16x8*)(Vb + nd * 2048 + lr * 128 +
                                     ((s * 64 + g * 16) ^ swz));
          acco[nd] = __builtin_amdgcn_mfma_f32_16x16x32_bf16(vf, pf,
                                                             acco[nd], 0, 0, 0);
        }
      }
      __builtin_amdgcn_s_setprio(0);

      __builtin_amdgcn_s_barrier();  // all waves done reading kvbuf[kt&1]
      if (kt + 2 <= tile) KVSTAGE(kt & 1, kt + 2);
    }

    lsum += __shfl_xor(lsum, 16, 64);
    lsum += __shfl_xor(lsum, 32, 64);
    float inv = 1.0f / lsum;
    size_t orow = ((size_t)b * SDIM + q0w + lr) * EDIM + h * DDIM;
#pragma unroll
    for (int nd = 0; nd < 4; ++nd) {
      unsigned lo = cvtpk(acco[nd][0] * inv, acco[nd][1] * inv);
      unsigned hi = cvtpk(acco[nd][2] * inv, acco[nd][3] * inv);
      *(unsigned*)(ao + orow + nd * 16 + g * 4) = lo;
      *(unsigned*)(ao + orow + nd * 16 + g * 4 + 2) = hi;
    }
  }
#undef KVSTAGE
}

extern "C" void kernel_launch(void* const* d_in, const int* in_sizes, int n_in,
                              void* d_out, int out_size, void* d_ws,
                              size_t ws_size, hipStream_t stream) {
  const float* x = (const float*)d_in[0];
  const float* w_qkv = (const float*)d_in[1];
  const float* b_qkv = (const float*)d_in[2];
  const float* w_proj = (const float*)d_in[3];
  const float* b_proj = (const float*)d_in[4];
  float* out = (float*)d_out;

  char* p = (char*)d_ws;
  short* xb = (short*)p;      p += (size_t)MROWS * EDIM * 2;
  short* wqkvt = (short*)p;   p += (size_t)NQKV * EDIM * 2;
  short* wprojt = (short*)p;  p += (size_t)EDIM * EDIM * 2;
  short* qbuf = (short*)p;    p += (size_t)NBH * SDIM * DDIM * 2;
  short* kbuf = (short*)p;    p += (size_t)NBH * SDIM * DDIM * 2;
  short* vbuf = (short*)p;    p += (size_t)NBH * SDIM * DDIM * 2;
  short* aob = (short*)p;     p += (size_t)MROWS * EDIM * 2;

  dim3 blk(256);
  preproc<<<dim3(1536 + 1728 + 576), blk, 0, stream>>>(x, w_qkv, w_proj, xb,
                                                       wqkvt, wprojt);
  // QKV: 128x128 tiles -> 64 * 18 = 1152 blocks (% 8 == 0)
  gemm_qkv<<<dim3((MROWS / 128) * (NQKV / 128)), blk, 0, stream>>>(
      xb, wqkvt, b_qkv, qbuf, kbuf, vbuf);
  attn_mfma4<<<dim3(NPAIR * NBH), blk, 0, stream>>>(qbuf, kbuf, vbuf, aob);
  // proj: 128x128 tiles -> 64 * 6 = 384 blocks (% 8 == 0)
  gemm_proj<<<dim3((MROWS / 128) * (EDIM / 128)), blk, 0, stream>>>(
      aob, wprojt, b_proj, MROWS, EDIM, EDIM, out);
}